// Round 9
// baseline (238.797 us; speedup 1.0000x reference)
//
#include <hip/hip_runtime.h>

typedef __bf16 bf16x8 __attribute__((ext_vector_type(8)));
typedef float f32x4 __attribute__((ext_vector_type(4)));
typedef unsigned short u16;

__device__ __forceinline__ u16 f2bf(float f){
  union { float fp; unsigned int u; } v; v.fp = f;
  unsigned int r = v.u + 0x7fffu + ((v.u >> 16) & 1u);
  return (u16)(r >> 16);
}

// pack two fp32 -> two bf16 (truncation) in ONE v_perm_b32
__device__ __forceinline__ unsigned pk2(float a, float b){
  union { float f; unsigned u; } ua, ub; ua.f = a; ub.f = b;
  return __builtin_amdgcn_perm(ub.u, ua.u, 0x07060302u);  // {b.hi16, a.hi16}
}

// async global->LDS DMA, 16B per lane; LDS dest = wave-uniform base + lane*16
__device__ __forceinline__ void glds16(const void* g, void* l){
  __builtin_amdgcn_global_load_lds((__attribute__((address_space(1))) void*)(void*)(g),
                                   (__attribute__((address_space(3))) void*)(l), 16, 0, 0);
}

// ---------------- fused prep: convert x, transpose weights, rope tables ----------------
__global__ __launch_bounds__(256) void prep_k(const float* __restrict__ x,
                                              const float* __restrict__ W0, const float* __restrict__ W1,
                                              const float* __restrict__ W2, const float* __restrict__ W3,
                                              u16* __restrict__ XB, u16* __restrict__ Wt,
                                              float* __restrict__ cosT, float* __restrict__ sinT){
  const int b = blockIdx.x, tid = threadIdx.x;
  if (b < 512){
    for (int i = b*256 + tid; i < (1<<20); i += 512*256){
      float4 v = ((const float4*)x)[i];
      ushort4 o;
      o.x = f2bf(v.x); o.y = f2bf(v.y); o.z = f2bf(v.z); o.w = f2bf(v.w);
      ((ushort4*)XB)[i] = o;
    }
  } else if (b < 4608){
    __shared__ float tile[32][33];
    const int b2 = b - 512;
    const int bz = b2>>10, by = (b2>>5)&31, bx = b2&31;
    const float* W = (bz==0)?W0:(bz==1)?W1:(bz==2)?W2:W3;
    u16* dst = Wt + ((size_t)bz<<20);
    const int tx = tid&31, ty = tid>>5;       // 32 x 8
    const int xx = bx*32 + tx;
    const int y0 = by*32;
    #pragma unroll
    for (int i=0;i<32;i+=8) tile[ty+i][tx] = W[(size_t)(y0+ty+i)*1024 + xx];
    __syncthreads();
    const int xo = y0 + tx;
    #pragma unroll
    for (int i=0;i<32;i+=8) dst[(size_t)(bx*32+ty+i)*1024 + xo] = f2bf(tile[tx][ty+i]);
  } else {
    const int i = (b-4608)*256 + tid;          // 131072 total
    const int si = i>>6, dd = i&63, f = dd&31;
    float invf = exp2f(-13.287712379549449f * (float)f * (1.0f/32.0f)); // 10000^(-f/32)
    float ang = (float)si * invf;
    float s, c;
    sincosf(ang, &s, &c);
    cosT[i] = c; sinT[i] = s;
  }
}

// ---------------- QKV GEMM (x@W) + RoPE + fragment-swizzled layouts ----------------
// BK=64 via two 32-col LDS panels (conflict-free 32-u16 pitch, glds16-compatible).
// Q,K -> FRAG16[bh][tile16][kh][lane][8], Q pre-scaled log2(e)/8; V -> VF[bh][kt64][kh][tjd][lane][8]
__global__ __launch_bounds__(256,3) void gemm_qkv_k(const u16* __restrict__ xb, const u16* __restrict__ Wt,
                                                  const float* __restrict__ cosT, const float* __restrict__ sinT,
                                                  u16* __restrict__ Qr, u16* __restrict__ Kr, u16* __restrict__ Vt){
  __shared__ __align__(16) u16 As[2*128*32];   // [kh][row][32]
  __shared__ __align__(16) u16 Bs[2*128*32];
  const int tid = threadIdx.x;
  const int w = tid>>6, lane = tid&63, quad = lane>>4, l15 = lane&15;
  const int wrow = w>>1, wcol = w&1;
  const int m0 = blockIdx.x*128;
  const int nG0 = blockIdx.y*128;
  const int which = nG0>>10, n0 = nG0&1023;
  const u16* __restrict__ B = Wt + ((size_t)which<<20);
  f32x4 acc[4][4] = {};
  const int r4 = lane>>2, c4 = (lane&3)*8;     // 16 rows / call, 4 lanes per row

  for (int kb=0; kb<1024; kb+=64){
    #pragma unroll
    for (int kh=0; kh<2; kh++){
      glds16(&xb[(size_t)(m0+32*w+r4)*1024    + kb + kh*32 + c4], &As[kh*4096 + (32*w)*32]);
      glds16(&xb[(size_t)(m0+32*w+16+r4)*1024 + kb + kh*32 + c4], &As[kh*4096 + (32*w+16)*32]);
      glds16(&B [(size_t)(n0+32*w+r4)*1024    + kb + kh*32 + c4], &Bs[kh*4096 + (32*w)*32]);
      glds16(&B [(size_t)(n0+32*w+16+r4)*1024 + kb + kh*32 + c4], &Bs[kh*4096 + (32*w+16)*32]);
    }
    __syncthreads();
    bf16x8 a[4][2], b[4][2];
    #pragma unroll
    for (int t=0;t<4;t++)
      #pragma unroll
      for (int kh=0;kh<2;kh++){
        a[t][kh] = *(const bf16x8*)&As[kh*4096 + (64*wrow + 16*t + l15)*32 + quad*8];
        b[t][kh] = *(const bf16x8*)&Bs[kh*4096 + (64*wcol + 16*t + l15)*32 + quad*8];
      }
    #pragma unroll
    for (int kh=0;kh<2;kh++)
      #pragma unroll
      for (int ti=0;ti<4;ti++)
        #pragma unroll
        for (int tj=0;tj<4;tj++)
          acc[ti][tj] = __builtin_amdgcn_mfma_f32_16x16x32_bf16(a[ti][kh], b[tj][kh], acc[ti][tj], 0,0,0);
    __syncthreads();
  }

  const int colbase = n0 + 64*wcol;     // 64-aligned
  const int hh = colbase>>6;
  const int rowbase = m0 + 64*wrow + 4*quad;
  const float QSCALE = 0.18033688011112042f;  // log2(e)/8 folded into Q

  if (which < 2){
    u16* __restrict__ out = (which==0) ? Qr : Kr;
    const float osc = (which==0) ? QSCALE : 1.0f;
    #pragma unroll
    for (int tj=0;tj<4;tj++){
      int dd = 16*tj + l15;
      int obase = (dd>>5)*512 + ((dd>>3)&3)*128 + (dd&7);  // kh*512 + qd*128 + j
      float sgn = (tj<2) ? -1.0f : 1.0f;
      int pj = tj^2;
      #pragma unroll
      for (int ti=0;ti<4;ti++){
        #pragma unroll
        for (int r=0;r<4;r++){
          int m = rowbase + 16*ti + r;
          int bi = m>>11, si = m&2047;
          float cs = cosT[(si<<6)+dd];
          float sn = sinT[(si<<6)+dd];
          float vv = (acc[ti][tj][r]*cs + sgn*acc[ti][pj][r]*sn) * osc;
          out[((size_t)(bi*16+hh)<<17) + (si>>4)*1024 + (si&15)*8 + obase] = f2bf(vv);
        }
      }
    }
  } else {
    #pragma unroll
    for (int tj=0;tj<4;tj++){
      #pragma unroll
      for (int ti=0;ti<4;ti++){
        int m = rowbase + 16*ti;        // key base; r=0..3 consecutive keys
        int bi = m>>11, si = m&2047;
        ushort4 pk;
        pk.x = f2bf(acc[ti][tj][0]); pk.y = f2bf(acc[ti][tj][1]);
        pk.z = f2bf(acc[ti][tj][2]); pk.w = f2bf(acc[ti][tj][3]);
        *(ushort4*)&Vt[((size_t)(bi*16+hh)<<17) + (si>>6)*4096 + ((si>>5)&1)*2048
                       + tj*512 + ((si>>3)&3)*128 + l15*8 + (si&7)] = pk;
      }
    }
  }
}

// ---------------- flash attention v7: low-VGPR per-ti pipeline, 4 waves/SIMD target ----------------
// grid 1024; each XCD owns 4 bh (K/V L2-resident). Block = ONE pair-unit = 4 waves;
// wave w takes k-tiles kt == w (mod 4). Two-pass O-merge through the 4.6KB P regions.
__global__ __launch_bounds__(256,4) void attn_k(const u16* __restrict__ QF, const u16* __restrict__ KF,
                                                const u16* __restrict__ VF, u16* __restrict__ ctx){
  __shared__ __align__(16) u16 SC[4*2304];      // 4 per-wave 4608B regions: P in-loop, half-O in merge
  __shared__ float LL[4][16];
  const int tid = threadIdx.x;
  const int w = tid>>6, lane = tid&63, quad = lane>>4, l15 = lane&15;
  const int Lin = blockIdx.x;
  const int xcd = Lin & 7, slot = Lin >> 3;     // 128 slots per XCD
  const int bh = (xcd<<2) | (slot>>5);          // 4 bh per XCD
  const int p = slot & 31;                      // pair index 0..31
  const u16* __restrict__ Qb = QF + ((size_t)bh<<17);
  const u16* __restrict__ Kb = KF + ((size_t)bh<<17);
  const u16* __restrict__ Vb = VF + ((size_t)bh<<17);
  u16* __restrict__ Pw = SC + w*2304;
  const int loff = lane*8;
  const int bi = bh>>4, hh = bh&15;

  #pragma unroll 1
  for (int ph=0; ph<2; ph++){
    if (ph) __syncthreads();                    // protect prev phase's merge reads
    const int tile = ph ? (63-p) : p;
    const int q0 = tile*32;
    const int nk = (tile>>1) + 1;

    bf16x8 qf[2][2];
    #pragma unroll
    for (int ti=0;ti<2;ti++)
      #pragma unroll
      for (int kh=0;kh<2;kh++)
        qf[ti][kh] = *(const bf16x8*)&Qb[(2*tile+ti)*1024 + kh*512 + loff];

    f32x4 o[2][4] = {};
    float ls[2] = {0.f, 0.f};

    #pragma unroll 1
    for (int kt = w; kt < nk; kt += 4){
      const int k0 = kt*64;
      bf16x8 kf[4][2];
      #pragma unroll
      for (int tjk=0;tjk<4;tjk++)
        #pragma unroll
        for (int kh=0;kh<2;kh++)
          kf[tjk][kh] = *(const bf16x8*)&Kb[(4*kt+tjk)*1024 + kh*512 + loff];

      // ---- ti = 0: S^T tiles, softmax, pack ----
      {
        f32x4 st[4] = {};
        #pragma unroll
        for (int tjk=0;tjk<4;tjk++){
          st[tjk] = __builtin_amdgcn_mfma_f32_16x16x32_bf16(kf[tjk][0], qf[0][0], st[tjk], 0,0,0);
          st[tjk] = __builtin_amdgcn_mfma_f32_16x16x32_bf16(kf[tjk][1], qf[0][1], st[tjk], 0,0,0);
        }
        f32x4 pv[4];
        if (k0 + 63 > q0){
          const int qg = q0 + l15;
          #pragma unroll
          for (int tjk=0;tjk<4;tjk++)
            #pragma unroll
            for (int r=0;r<4;r++){
              int kg = k0 + 16*tjk + 4*quad + r;
              pv[tjk][r] = (kg > qg) ? 0.0f : exp2f(st[tjk][r]);
            }
        } else {
          #pragma unroll
          for (int tjk=0;tjk<4;tjk++)
            #pragma unroll
            for (int r=0;r<4;r++)
              pv[tjk][r] = exp2f(st[tjk][r]);
        }
        f32x4 t4 = (pv[0]+pv[1]) + (pv[2]+pv[3]);
        float rs = (t4[0]+t4[1]) + (t4[2]+t4[3]);
        rs += __shfl_xor(rs, 16, 64);
        rs += __shfl_xor(rs, 32, 64);
        ls[0] += rs;
        #pragma unroll
        for (int tjk=0;tjk<4;tjk++){
          uint2 pk;
          pk.x = pk2(pv[tjk][0], pv[tjk][1]);
          pk.y = pk2(pv[tjk][2], pv[tjk][3]);
          *(uint2*)&Pw[l15*72 + 16*tjk + 4*quad] = pk;
        }
      }

      // ---- ti = 1: S^T tiles (kf dies here), then vf loads, softmax, pack ----
      bf16x8 vf[4][2];
      {
        f32x4 st[4] = {};
        #pragma unroll
        for (int tjk=0;tjk<4;tjk++){
          st[tjk] = __builtin_amdgcn_mfma_f32_16x16x32_bf16(kf[tjk][0], qf[1][0], st[tjk], 0,0,0);
          st[tjk] = __builtin_amdgcn_mfma_f32_16x16x32_bf16(kf[tjk][1], qf[1][1], st[tjk], 0,0,0);
        }
        #pragma unroll
        for (int tjd=0;tjd<4;tjd++)
          #pragma unroll
          for (int kh=0;kh<2;kh++)
            vf[tjd][kh] = *(const bf16x8*)&Vb[kt*4096 + kh*2048 + tjd*512 + loff];
        f32x4 pv[4];
        if (k0 + 63 > q0 + 16){
          const int qg = q0 + 16 + l15;
          #pragma unroll
          for (int tjk=0;tjk<4;tjk++)
            #pragma unroll
            for (int r=0;r<4;r++){
              int kg = k0 + 16*tjk + 4*quad + r;
              pv[tjk][r] = (kg > qg) ? 0.0f : exp2f(st[tjk][r]);
            }
        } else {
          #pragma unroll
          for (int tjk=0;tjk<4;tjk++)
            #pragma unroll
            for (int r=0;r<4;r++)
              pv[tjk][r] = exp2f(st[tjk][r]);
        }
        f32x4 t4 = (pv[0]+pv[1]) + (pv[2]+pv[3]);
        float rs = (t4[0]+t4[1]) + (t4[2]+t4[3]);
        rs += __shfl_xor(rs, 16, 64);
        rs += __shfl_xor(rs, 32, 64);
        ls[1] += rs;
        #pragma unroll
        for (int tjk=0;tjk<4;tjk++){
          uint2 pk;
          pk.x = pk2(pv[tjk][0], pv[tjk][1]);
          pk.y = pk2(pv[tjk][2], pv[tjk][3]);
          *(uint2*)&Pw[(16 + l15)*72 + 16*tjk + 4*quad] = pk;
        }
      }

      // ---- O += P V ----
      bf16x8 pf[2][2];
      #pragma unroll
      for (int ti=0;ti<2;ti++)
        #pragma unroll
        for (int kh=0;kh<2;kh++)
          pf[ti][kh] = *(const bf16x8*)&Pw[(16*ti + l15)*72 + 32*kh + quad*8];
      #pragma unroll
      for (int ti=0;ti<2;ti++)
        #pragma unroll
        for (int tjd=0;tjd<4;tjd++){
          o[ti][tjd] = __builtin_amdgcn_mfma_f32_16x16x32_bf16(pf[ti][0], vf[tjd][0], o[ti][tjd], 0,0,0);
          o[ti][tjd] = __builtin_amdgcn_mfma_f32_16x16x32_bf16(pf[ti][1], vf[tjd][1], o[ti][tjd], 0,0,0);
        }
    }

    // ---- two-pass merge through the 4.6KB regions: pass tix = q-half ----
    #pragma unroll 1
    for (int tix=0; tix<2; tix++){
      if (tix) __syncthreads();                 // after pass-0 merge reads
      float* __restrict__ Ob = (float*)&SC[w*2304];
      #pragma unroll
      for (int tjd=0;tjd<4;tjd++)
        *(f32x4*)&Ob[(16*tjd + l15)*18 + 4*quad] = o[tix][tjd];   // 64 d-rows x 16 q, pitch 18
      if (quad == 0) LL[w][l15] = ls[tix];
      __syncthreads();
      // wave w merges d-rows [16w, 16w+16)
      f32x4 om = {0.f,0.f,0.f,0.f};
      #pragma unroll
      for (int w2=0;w2<4;w2++)
        om += *(const f32x4*)&((const float*)&SC[w2*2304])[(16*w + l15)*18 + 4*quad];
      #pragma unroll
      for (int r=0;r<4;r++){
        int ridx = 4*quad + r;
        float lv = LL[0][ridx] + LL[1][ridx] + LL[2][ridx] + LL[3][ridx];
        int sq = q0 + 16*tix + ridx;
        ctx[(((size_t)(bi*2048 + sq))<<10) + (hh<<6) + 16*w + l15] = f2bf(om[r] / lv);
      }
    }
  }
}

// ---------------- output GEMM: ctx @ W_o -> fp32 out (64x128 tiles, BK=64) ----------------
__global__ __launch_bounds__(256,3) void gemm_out_k(const u16* __restrict__ cb, const u16* __restrict__ Wot,
                                                  float* __restrict__ out){
  __shared__ __align__(16) u16 As[2*64*32];    // [kh][row][32]
  __shared__ __align__(16) u16 Bs[2*128*32];
  const int tid = threadIdx.x;
  const int w = tid>>6, lane = tid&63, quad = lane>>4, l15 = lane&15;
  const int wrow = w>>1, wcol = w&1;
  const int m0 = blockIdx.x*64;
  const int nG0 = blockIdx.y*128;
  f32x4 acc[2][4] = {};
  const int r4 = lane>>2, c4 = (lane&3)*8;

  for (int kb=0; kb<1024; kb+=64){
    #pragma unroll
    for (int kh=0; kh<2; kh++){
      glds16(&cb [(size_t)(m0+16*w+r4)*1024     + kb + kh*32 + c4], &As[kh*2048 + (16*w)*32]);
      glds16(&Wot[(size_t)(nG0+32*w+r4)*1024    + kb + kh*32 + c4], &Bs[kh*4096 + (32*w)*32]);
      glds16(&Wot[(size_t)(nG0+32*w+16+r4)*1024 + kb + kh*32 + c4], &Bs[kh*4096 + (32*w+16)*32]);
    }
    __syncthreads();
    bf16x8 a[2][2], b[4][2];
    #pragma unroll
    for (int kh=0;kh<2;kh++){
      #pragma unroll
      for (int t=0;t<2;t++)
        a[t][kh] = *(const bf16x8*)&As[kh*2048 + (32*wrow + 16*t + l15)*32 + quad*8];
      #pragma unroll
      for (int t=0;t<4;t++)
        b[t][kh] = *(const bf16x8*)&Bs[kh*4096 + (64*wcol + 16*t + l15)*32 + quad*8];
    }
    #pragma unroll
    for (int kh=0;kh<2;kh++)
      #pragma unroll
      for (int ti=0;ti<2;ti++)
        #pragma unroll
        for (int tj=0;tj<4;tj++)
          acc[ti][tj] = __builtin_amdgcn_mfma_f32_16x16x32_bf16(a[ti][kh], b[tj][kh], acc[ti][tj], 0,0,0);
    __syncthreads();
  }

  const int rowbase = m0 + 32*wrow + 4*quad;
  const int colb = nG0 + 64*wcol;
  #pragma unroll
  for (int ti=0;ti<2;ti++){
    #pragma unroll
    for (int r=0;r<4;r++){
      int m = rowbase + 16*ti + r;
      float* orow = out + (size_t)m*1024 + colb;
      #pragma unroll
      for (int tj=0;tj<4;tj++)
        orow[16*tj + l15] = acc[ti][tj][r];
    }
  }
}

extern "C" void kernel_launch(void* const* d_in, const int* in_sizes, int n_in,
                              void* d_out, int out_size, void* d_ws, size_t ws_size,
                              hipStream_t stream){
  const float* x  = (const float*)d_in[0];
  const float* Wq = (const float*)d_in[1];
  const float* Wk = (const float*)d_in[2];
  const float* Wv = (const float*)d_in[3];
  const float* Wo = (const float*)d_in[4];
  float* out = (float*)d_out;
  u16* ws = (u16*)d_ws;

  u16* XB  = ws;                    // x bf16            [4096][1024]   8 MB
  u16* WT  = ws + ((size_t)4<<20);  // Wq^T,Wk^T,Wv^T,Wo^T bf16         8 MB
  u16* QFp = ws + ((size_t)8<<20);  // Q fragments (roped+scaled)       8 MB
  u16* KFp = ws + ((size_t)12<<20); // K fragments (roped)              8 MB
  u16* VFp = ws + ((size_t)16<<20); // V fragments                      8 MB
  u16* CTX = ws + ((size_t)20<<20); // ctx bf16 [4096][1024]            8 MB
  float* COS = (float*)(ws + ((size_t)24<<20));  // [2048][64]          512 KB
  float* SIN = COS + (1<<17);                    //                     512 KB

  prep_k       <<<5120, 256, 0, stream>>>(x, Wq, Wk, Wv, Wo, XB, WT, COS, SIN);
  gemm_qkv_k   <<<dim3(32,24), 256, 0, stream>>>(XB, WT, COS, SIN, QFp, KFp, VFp);
  attn_k       <<<1024, 256, 0, stream>>>(QFp, KFp, VFp, CTX);
  gemm_out_k   <<<dim3(64,8), 256, 0, stream>>>(CTX, WT + ((size_t)3<<20), out);
}

// Round 10
// 174.963 us; speedup vs baseline: 1.3648x; 1.3648x over previous
//
#include <hip/hip_runtime.h>

typedef __bf16 bf16x8 __attribute__((ext_vector_type(8)));
typedef float f32x4 __attribute__((ext_vector_type(4)));
typedef unsigned short u16;

__device__ __forceinline__ u16 f2bf(float f){
  union { float fp; unsigned int u; } v; v.fp = f;
  unsigned int r = v.u + 0x7fffu + ((v.u >> 16) & 1u);
  return (u16)(r >> 16);
}

// pack two fp32 -> two bf16 (truncation) in ONE v_perm_b32
__device__ __forceinline__ unsigned pk2(float a, float b){
  union { float f; unsigned u; } ua, ub; ua.f = a; ub.f = b;
  return __builtin_amdgcn_perm(ub.u, ua.u, 0x07060302u);  // {b.hi16, a.hi16}
}

// async global->LDS DMA, 16B per lane; LDS dest = wave-uniform base + lane*16
__device__ __forceinline__ void glds16(const void* g, void* l){
  __builtin_amdgcn_global_load_lds((__attribute__((address_space(1))) void*)(void*)(g),
                                   (__attribute__((address_space(3))) void*)(l), 16, 0, 0);
}

// ---------------- fused prep: convert x, transpose weights, rope tables ----------------
__global__ __launch_bounds__(256) void prep_k(const float* __restrict__ x,
                                              const float* __restrict__ W0, const float* __restrict__ W1,
                                              const float* __restrict__ W2, const float* __restrict__ W3,
                                              u16* __restrict__ XB, u16* __restrict__ Wt,
                                              float* __restrict__ cosT, float* __restrict__ sinT){
  const int b = blockIdx.x, tid = threadIdx.x;
  if (b < 512){
    for (int i = b*256 + tid; i < (1<<20); i += 512*256){
      float4 v = ((const float4*)x)[i];
      ushort4 o;
      o.x = f2bf(v.x); o.y = f2bf(v.y); o.z = f2bf(v.z); o.w = f2bf(v.w);
      ((ushort4*)XB)[i] = o;
    }
  } else if (b < 4608){
    __shared__ float tile[32][33];
    const int b2 = b - 512;
    const int bz = b2>>10, by = (b2>>5)&31, bx = b2&31;
    const float* W = (bz==0)?W0:(bz==1)?W1:(bz==2)?W2:W3;
    u16* dst = Wt + ((size_t)bz<<20);
    const int tx = tid&31, ty = tid>>5;       // 32 x 8
    const int xx = bx*32 + tx;
    const int y0 = by*32;
    #pragma unroll
    for (int i=0;i<32;i+=8) tile[ty+i][tx] = W[(size_t)(y0+ty+i)*1024 + xx];
    __syncthreads();
    const int xo = y0 + tx;
    #pragma unroll
    for (int i=0;i<32;i+=8) dst[(size_t)(bx*32+ty+i)*1024 + xo] = f2bf(tile[tx][ty+i]);
  } else {
    const int i = (b-4608)*256 + tid;          // 131072 total
    const int si = i>>6, dd = i&63, f = dd&31;
    float invf = exp2f(-13.287712379549449f * (float)f * (1.0f/32.0f)); // 10000^(-f/32)
    float ang = (float)si * invf;
    float s, c;
    sincosf(ang, &s, &c);
    cosT[i] = c; sinT[i] = s;
  }
}

// ---------------- QKV GEMM (x@W) + RoPE + fragment-swizzled layouts ----------------
// BK=64 via two 32-col LDS panels; Q/K epilogue via LDS for coalesced 16B stores.
// Q,K -> FRAG16[bh][tile16][kh][lane][8], Q pre-scaled log2(e)/8; V -> VF[bh][kt64][kh][tjd][lane][8]
__global__ __launch_bounds__(256,3) void gemm_qkv_k(const u16* __restrict__ xb, const u16* __restrict__ Wt,
                                                  const float* __restrict__ cosT, const float* __restrict__ sinT,
                                                  u16* __restrict__ Qr, u16* __restrict__ Kr, u16* __restrict__ Vt){
  __shared__ __align__(16) u16 As[2*128*32];   // [kh][row][32]; reused as Q/K epilogue scratch
  __shared__ __align__(16) u16 Bs[2*128*32];
  const int tid = threadIdx.x;
  const int w = tid>>6, lane = tid&63, quad = lane>>4, l15 = lane&15;
  const int wrow = w>>1, wcol = w&1;
  const int m0 = blockIdx.x*128;
  const int nG0 = blockIdx.y*128;
  const int which = nG0>>10, n0 = nG0&1023;
  const u16* __restrict__ B = Wt + ((size_t)which<<20);
  f32x4 acc[4][4] = {};
  const int r4 = lane>>2, c4 = (lane&3)*8;     // 16 rows / call, 4 lanes per row

  for (int kb=0; kb<1024; kb+=64){
    #pragma unroll
    for (int kh=0; kh<2; kh++){
      glds16(&xb[(size_t)(m0+32*w+r4)*1024    + kb + kh*32 + c4], &As[kh*4096 + (32*w)*32]);
      glds16(&xb[(size_t)(m0+32*w+16+r4)*1024 + kb + kh*32 + c4], &As[kh*4096 + (32*w+16)*32]);
      glds16(&B [(size_t)(n0+32*w+r4)*1024    + kb + kh*32 + c4], &Bs[kh*4096 + (32*w)*32]);
      glds16(&B [(size_t)(n0+32*w+16+r4)*1024 + kb + kh*32 + c4], &Bs[kh*4096 + (32*w+16)*32]);
    }
    __syncthreads();
    bf16x8 a[4][2], b[4][2];
    #pragma unroll
    for (int t=0;t<4;t++)
      #pragma unroll
      for (int kh=0;kh<2;kh++){
        a[t][kh] = *(const bf16x8*)&As[kh*4096 + (64*wrow + 16*t + l15)*32 + quad*8];
        b[t][kh] = *(const bf16x8*)&Bs[kh*4096 + (64*wcol + 16*t + l15)*32 + quad*8];
      }
    #pragma unroll
    for (int kh=0;kh<2;kh++)
      #pragma unroll
      for (int ti=0;ti<4;ti++)
        #pragma unroll
        for (int tj=0;tj<4;tj++)
          acc[ti][tj] = __builtin_amdgcn_mfma_f32_16x16x32_bf16(a[ti][kh], b[tj][kh], acc[ti][tj], 0,0,0);
    __syncthreads();
  }

  const int colbase = n0 + 64*wcol;     // 64-aligned -> one head per wave-column
  const int hh = colbase>>6;
  const int rowbase = m0 + 64*wrow + 4*quad;
  const float QSCALE = 0.18033688011112042f;  // log2(e)/8 folded into Q

  if (which < 2){
    u16* __restrict__ out = (which==0) ? Qr : Kr;
    const float osc = (which==0) ? QSCALE : 1.0f;
    // wave-private 8KB epilogue region (reuse As/Bs; k-loop's trailing barrier protects)
    u16* __restrict__ EP = (w<2) ? &As[w*4096] : &Bs[(w-2)*4096];
    #pragma unroll
    for (int tj=0;tj<4;tj++){
      int dd = 16*tj + l15;
      int co = (dd>>5)*512 + ((dd>>3)&3)*128 + (dd&7);  // kh*512 + qd*128 + j
      float sgn = (tj<2) ? -1.0f : 1.0f;
      int pj = tj^2;
      #pragma unroll
      for (int ti=0;ti<4;ti++){
        #pragma unroll
        for (int r=0;r<4;r++){
          int m = rowbase + 16*ti + r;
          int si = m&2047;
          float cs = cosT[(si<<6)+dd];
          float sn = sinT[(si<<6)+dd];
          float vv = (acc[ti][tj][r]*cs + sgn*acc[ti][pj][r]*sn) * osc;
          EP[ti*1024 + co + (4*quad+r)*8] = f2bf(vv);   // frag order within tile16
        }
      }
    }
    // same-wave LDS round-trip (no barrier needed), then coalesced 16B global stores
    #pragma unroll
    for (int ti=0;ti<4;ti++){
      int mbase = m0 + 64*wrow + 16*ti;
      int bi = mbase>>11, si16 = (mbase&2047)>>4;
      size_t gb = ((size_t)(bi*16+hh)<<17) + (size_t)si16*1024;
      #pragma unroll
      for (int g=0; g<2; g++){
        uint4 vvv = *(const uint4*)&EP[ti*1024 + g*512 + lane*8];
        *(uint4*)&out[gb + g*512 + lane*8] = vvv;
      }
    }
  } else {
    #pragma unroll
    for (int tj=0;tj<4;tj++){
      #pragma unroll
      for (int ti=0;ti<4;ti++){
        int m = rowbase + 16*ti;        // key base; r=0..3 consecutive keys
        int bi = m>>11, si = m&2047;
        ushort4 pk;
        pk.x = f2bf(acc[ti][tj][0]); pk.y = f2bf(acc[ti][tj][1]);
        pk.z = f2bf(acc[ti][tj][2]); pk.w = f2bf(acc[ti][tj][3]);
        *(ushort4*)&Vt[((size_t)(bi*16+hh)<<17) + (si>>6)*4096 + ((si>>5)&1)*2048
                       + tj*512 + ((si>>3)&3)*128 + l15*8 + (si&7)] = pk;
      }
    }
  }
}

// ---------------- flash attention v6 (round-8 known-good): 4-way K-split, bounds(256,3) ----------------
// grid 1024 (1-D); each XCD owns 4 bh (K/V L2-resident). Block = ONE pair-unit = 4 waves;
// wave w takes k-tiles kt == w (mod 4); per-phase merge: wave w merges d-columns 16w..16w+15.
__global__ __launch_bounds__(256,3) void attn_k(const u16* __restrict__ QF, const u16* __restrict__ KF,
                                                const u16* __restrict__ VF, u16* __restrict__ ctx){
  __shared__ __align__(16) u16 SC[4*4608];      // 4 per-wave regions (P in-loop, O-partial after)
  __shared__ float LL[4][32];
  const int tid = threadIdx.x;
  const int w = tid>>6, lane = tid&63, quad = lane>>4, l15 = lane&15;
  const int Lin = blockIdx.x;
  const int xcd = Lin & 7, slot = Lin >> 3;     // 128 slots per XCD
  const int bh = (xcd<<2) | (slot>>5);          // 4 bh per XCD
  const int p = slot & 31;                      // pair index 0..31
  const u16* __restrict__ Qb = QF + ((size_t)bh<<17);
  const u16* __restrict__ Kb = KF + ((size_t)bh<<17);
  const u16* __restrict__ Vb = VF + ((size_t)bh<<17);
  u16* __restrict__ Pw = SC + w*4608;
  const int loff = lane*8;
  const int bi = bh>>4, hh = bh&15;

  #pragma unroll 1
  for (int ph=0; ph<2; ph++){
    if (ph) __syncthreads();                    // protect prev phase's merge reads
    const int tile = ph ? (63-p) : p;
    const int q0 = tile*32;
    const int nk = (tile>>1) + 1;

    bf16x8 qf[2][2];
    #pragma unroll
    for (int ti=0;ti<2;ti++)
      #pragma unroll
      for (int kh=0;kh<2;kh++)
        qf[ti][kh] = *(const bf16x8*)&Qb[(2*tile+ti)*1024 + kh*512 + loff];

    f32x4 o[2][4] = {};
    float ls[2] = {0.f, 0.f};

    for (int kt = w; kt < nk; kt += 4){
      const int k0 = kt*64;
      bf16x8 kf[4][2], vf[4][2];
      #pragma unroll
      for (int tjk=0;tjk<4;tjk++)
        #pragma unroll
        for (int kh=0;kh<2;kh++)
          kf[tjk][kh] = *(const bf16x8*)&Kb[(4*kt+tjk)*1024 + kh*512 + loff];
      #pragma unroll
      for (int tjd=0;tjd<4;tjd++)
        #pragma unroll
        for (int kh=0;kh<2;kh++)
          vf[tjd][kh] = *(const bf16x8*)&Vb[kt*4096 + kh*2048 + tjd*512 + loff];

      // S^T = K Q^T : col = q = l15, row = key = 16*tjk + 4*quad + r
      f32x4 st[2][4] = {};
      #pragma unroll
      for (int ti=0;ti<2;ti++)
        #pragma unroll
        for (int tjk=0;tjk<4;tjk++){
          st[ti][tjk] = __builtin_amdgcn_mfma_f32_16x16x32_bf16(kf[tjk][0], qf[ti][0], st[ti][tjk], 0,0,0);
          st[ti][tjk] = __builtin_amdgcn_mfma_f32_16x16x32_bf16(kf[tjk][1], qf[ti][1], st[ti][tjk], 0,0,0);
        }

      // max-free softmax (scale folded into Q): p = exp2(s), causal-masked on diagonal tiles
      #pragma unroll
      for (int ti=0;ti<2;ti++){
        const int qbase = q0 + 16*ti;
        f32x4 pv[4];
        if (k0 + 63 > qbase){                 // mask iff max key > min q-row of this 16-group
          const int qg = qbase + l15;
          #pragma unroll
          for (int tjk=0;tjk<4;tjk++)
            #pragma unroll
            for (int r=0;r<4;r++){
              int kg = k0 + 16*tjk + 4*quad + r;
              pv[tjk][r] = (kg > qg) ? 0.0f : exp2f(st[ti][tjk][r]);
            }
        } else {
          #pragma unroll
          for (int tjk=0;tjk<4;tjk++)
            #pragma unroll
            for (int r=0;r<4;r++)
              pv[tjk][r] = exp2f(st[ti][tjk][r]);
        }
        f32x4 t4 = (pv[0]+pv[1]) + (pv[2]+pv[3]);
        float rs = (t4[0]+t4[1]) + (t4[2]+t4[3]);
        rs += __shfl_xor(rs, 16, 64);
        rs += __shfl_xor(rs, 32, 64);
        ls[ti] += rs;
        #pragma unroll
        for (int tjk=0;tjk<4;tjk++){
          uint2 pk;
          pk.x = pk2(pv[tjk][0], pv[tjk][1]);
          pk.y = pk2(pv[tjk][2], pv[tjk][3]);
          *(uint2*)&Pw[(16*ti + l15)*72 + 16*tjk + 4*quad] = pk;
        }
      }

      // O += P V
      bf16x8 pf[2][2];
      #pragma unroll
      for (int ti=0;ti<2;ti++)
        #pragma unroll
        for (int kh=0;kh<2;kh++)
          pf[ti][kh] = *(const bf16x8*)&Pw[(16*ti + l15)*72 + 32*kh + quad*8];
      #pragma unroll
      for (int ti=0;ti<2;ti++)
        #pragma unroll
        for (int tjd=0;tjd<4;tjd++){
          o[ti][tjd] = __builtin_amdgcn_mfma_f32_16x16x32_bf16(pf[ti][0], vf[tjd][0], o[ti][tjd], 0,0,0);
          o[ti][tjd] = __builtin_amdgcn_mfma_f32_16x16x32_bf16(pf[ti][1], vf[tjd][1], o[ti][tjd], 0,0,0);
        }
    }

    // ---- per-phase merge: all 4 waves store partials; wave w merges d-cols [16w,16w+16) ----
    float* __restrict__ Ob = (float*)&SC[w*4608];
    #pragma unroll
    for (int ti=0;ti<2;ti++)
      #pragma unroll
      for (int tjd=0;tjd<4;tjd++)
        *(f32x4*)&Ob[(16*tjd + l15)*36 + 16*ti + 4*quad] = o[ti][tjd];
    if (quad == 0){
      LL[w][l15]      = ls[0];
      LL[w][16 + l15] = ls[1];
    }
    __syncthreads();

    #pragma unroll
    for (int ti=0;ti<2;ti++){
      f32x4 om = {0.f,0.f,0.f,0.f};
      #pragma unroll
      for (int w2=0;w2<4;w2++)
        om += *(const f32x4*)&((const float*)&SC[w2*4608])[(16*w + l15)*36 + 16*ti + 4*quad];
      #pragma unroll
      for (int r=0;r<4;r++){
        int ridx = 16*ti + 4*quad + r;
        float lv = LL[0][ridx] + LL[1][ridx] + LL[2][ridx] + LL[3][ridx];
        int sq = q0 + ridx;
        ctx[(((size_t)(bi*2048 + sq))<<10) + (hh<<6) + 16*w + l15] = f2bf(om[r] / lv);
      }
    }
  }
}

// ---------------- output GEMM: ctx @ W_o -> fp32 out (64x128 tiles, BK=64) ----------------
__global__ __launch_bounds__(256,3) void gemm_out_k(const u16* __restrict__ cb, const u16* __restrict__ Wot,
                                                  float* __restrict__ out){
  __shared__ __align__(16) u16 As[2*64*32];    // [kh][row][32]
  __shared__ __align__(16) u16 Bs[2*128*32];
  const int tid = threadIdx.x;
  const int w = tid>>6, lane = tid&63, quad = lane>>4, l15 = lane&15;
  const int wrow = w>>1, wcol = w&1;
  const int m0 = blockIdx.x*64;
  const int nG0 = blockIdx.y*128;
  f32x4 acc[2][4] = {};
  const int r4 = lane>>2, c4 = (lane&3)*8;

  for (int kb=0; kb<1024; kb+=64){
    #pragma unroll
    for (int kh=0; kh<2; kh++){
      glds16(&cb [(size_t)(m0+16*w+r4)*1024     + kb + kh*32 + c4], &As[kh*2048 + (16*w)*32]);
      glds16(&Wot[(size_t)(nG0+32*w+r4)*1024    + kb + kh*32 + c4], &Bs[kh*4096 + (32*w)*32]);
      glds16(&Wot[(size_t)(nG0+32*w+16+r4)*1024 + kb + kh*32 + c4], &Bs[kh*4096 + (32*w+16)*32]);
    }
    __syncthreads();
    bf16x8 a[2][2], b[4][2];
    #pragma unroll
    for (int kh=0;kh<2;kh++){
      #pragma unroll
      for (int t=0;t<2;t++)
        a[t][kh] = *(const bf16x8*)&As[kh*2048 + (32*wrow + 16*t + l15)*32 + quad*8];
      #pragma unroll
      for (int t=0;t<4;t++)
        b[t][kh] = *(const bf16x8*)&Bs[kh*4096 + (64*wcol + 16*t + l15)*32 + quad*8];
    }
    #pragma unroll
    for (int kh=0;kh<2;kh++)
      #pragma unroll
      for (int ti=0;ti<2;ti++)
        #pragma unroll
        for (int tj=0;tj<4;tj++)
          acc[ti][tj] = __builtin_amdgcn_mfma_f32_16x16x32_bf16(a[ti][kh], b[tj][kh], acc[ti][tj], 0,0,0);
    __syncthreads();
  }

  const int rowbase = m0 + 32*wrow + 4*quad;
  const int colb = nG0 + 64*wcol;
  #pragma unroll
  for (int ti=0;ti<2;ti++){
    #pragma unroll
    for (int r=0;r<4;r++){
      int m = rowbase + 16*ti + r;
      float* orow = out + (size_t)m*1024 + colb;
      #pragma unroll
      for (int tj=0;tj<4;tj++)
        orow[16*tj + l15] = acc[ti][tj][r];
    }
  }
}

extern "C" void kernel_launch(void* const* d_in, const int* in_sizes, int n_in,
                              void* d_out, int out_size, void* d_ws, size_t ws_size,
                              hipStream_t stream){
  const float* x  = (const float*)d_in[0];
  const float* Wq = (const float*)d_in[1];
  const float* Wk = (const float*)d_in[2];
  const float* Wv = (const float*)d_in[3];
  const float* Wo = (const float*)d_in[4];
  float* out = (float*)d_out;
  u16* ws = (u16*)d_ws;

  u16* XB  = ws;                    // x bf16            [4096][1024]   8 MB
  u16* WT  = ws + ((size_t)4<<20);  // Wq^T,Wk^T,Wv^T,Wo^T bf16         8 MB
  u16* QFp = ws + ((size_t)8<<20);  // Q fragments (roped+scaled)       8 MB
  u16* KFp = ws + ((size_t)12<<20); // K fragments (roped)              8 MB
  u16* VFp = ws + ((size_t)16<<20); // V fragments                      8 MB
  u16* CTX = ws + ((size_t)20<<20); // ctx bf16 [4096][1024]            8 MB
  float* COS = (float*)(ws + ((size_t)24<<20));  // [2048][64]          512 KB
  float* SIN = COS + (1<<17);                    //                     512 KB

  prep_k       <<<5120, 256, 0, stream>>>(x, Wq, Wk, Wv, Wo, XB, WT, COS, SIN);
  gemm_qkv_k   <<<dim3(32,24), 256, 0, stream>>>(XB, WT, COS, SIN, QFp, KFp, VFp);
  attn_k       <<<1024, 256, 0, stream>>>(QFp, KFp, VFp, CTX);
  gemm_out_k   <<<dim3(64,8), 256, 0, stream>>>(CTX, WT + ((size_t)3<<20), out);
}